// Round 7
// baseline (193.511 us; speedup 1.0000x reference)
//
#include <hip/hip_runtime.h>
#include <math.h>

// [B=2, 1, D=192, H=192, W=192] fp32
#define W 192
#define H 192
#define DEPTH 192
#define BATCH 2
#define TW 64          // tile width
#define TH 16          // tile height (8 waves, one row-pair per wave)
#define DC 12          // output planes per block
#define NT 512         // threads per block = 8 waves
#define HW (H * W)
#define VOL ((size_t)DEPTH * HW)
#define LROW 72        // LDS row stride (floats) = aligned halo row [w0-4, w0+68)
#define LROWS 18       // halo rows per plane tile (TH+2)
#define LPLANE (LROW * LROWS)         // 1296 floats per plane tile
#define NPAIR ((DC + 2) / 2)          // 7 pairs of planes: d0-1 .. d0+12
#define NITEM 1296                    // float4 items per pair: 2 arrays * 2 planes * 18 rows * 18
#define NBUF 2                        // double buffer (depth-1 prefetch covers latency; proven)
#define BUFFLOATS 6144                // 1536 DMA slots * 4 floats (1296 used + pad for OOB lanes)
#define GX ((W / TW) * (H / TH))      // 3*12 = 36
#define GY (DEPTH / DC)               // 16
#define NBLK (GX * GY * BATCH)        // 1152

// Zero page for OOB DMA sources (explicitly zero-initialized).
__device__ __align__(16) float g_zero16[16] = {0.f};

// Rounds 0/4/6 all land at ~72us with conflicts 0 and latency hidden; Occupancy is
// pinned at ~2.65 BLOCKS/CU across 11.7KB and 37KB LDS footprints -> test the
// block-residency hypothesis: 8-wave blocks (512 thr) to double waves/CU at the
// same block residency. Compute geometry per wave identical to round 4 (row-pair,
// conflict-free 64-consecutive-float LDS reads).
__global__ __launch_bounds__(NT) void sobel_loss_part(
    const float* __restrict__ pred, const float* __restrict__ gt,
    const float* __restrict__ mask, float* __restrict__ partials)
{
    __shared__ __align__(16) float lds[NBUF * BUFFLOATS];
    __shared__ float red[8];

    const int tid = threadIdx.x;
    const int tx = blockIdx.x % 3;          // W tile (0..2)
    const int ty = blockIdx.x / 3;          // H tile (0..11)
    const int w0 = tx * TW, h0 = ty * TH;
    const int d0 = blockIdx.y * DC;
    const size_t base = (size_t)blockIdx.z * VOL;

    // compute-thread geometry: wave wv owns rows (2wv, 2wv+1); lane = column
    const int wv  = tid >> 6;               // wave 0..7 -> row pair
    const int col = tid & 63;               // column 0..63
    const size_t moff = base + (size_t)(h0 + 2 * wv) * W + (w0 + col);  // row A; row B = +W

    // ---- staging geometry (3 DMA items/thread, loop-invariant) ----
    // j = tid + 512k < 1296: a=j/648 (0=pred,1=gt), q=plane in pair, r=row 0..17, c=col4 0..17
    // LDS float offset = 4*j (linear) == (2a+q)*LPLANE + r*LROW + 4c  (verified identity).
    int it_ok[3], it_q[3];
    size_t it_goff[3];
    const float* it_src[3];
    #pragma unroll
    for (int k = 0; k < 3; ++k) {
        int j = tid + NT * k;
        int jj = (j < NITEM) ? j : 0;
        int a = jj / 648; int pj = jj - a * 648;
        int q = pj / 324; int e = pj - q * 324;
        int r = e / 18;   int c = e - r * 18;
        int y  = h0 - 1 + r;
        int xf = w0 - 4 + 4 * c;            // 16B aligned; OOB float4s are fully OOB
        it_ok[k]  = (j < NITEM) && ((unsigned)y < (unsigned)H) && ((unsigned)xf < (unsigned)W);
        it_goff[k] = it_ok[k] ? ((size_t)y * W + xf) : 0;
        it_q[k]    = q;
        it_src[k]  = a ? gt : pred;
    }

    typedef const __attribute__((address_space(1))) void GV;
    typedef __attribute__((address_space(3))) void LV;

    auto dma_pair = [&](int s) {
        float* bufp = lds + (s & 1) * BUFFLOATS;
        const int p0 = d0 - 1 + 2 * s;
        #pragma unroll
        for (int k = 0; k < 3; ++k) {
            const int p = p0 + it_q[k];
            const bool v = it_ok[k] && (p >= 0) && (p < DEPTH);
            const float* ga = v ? (it_src[k] + base + (size_t)p * HW + it_goff[k])
                               : g_zero16;
            // LDS dest: wave-uniform base 16*(wv*64 + 512k) bytes + lane*16 (HW-applied)
            __builtin_amdgcn_global_load_lds((GV*)ga,
                (LV*)(bufp + (((wv << 6) + (k << 9)) << 2)), 16, 0, 0);
        }
    };

    float2 Mn = make_float2(0.f, 0.f), Mn1 = make_float2(0.f, 0.f);
    float2 Mc, Mc1;
    auto load_mask = [&](int s) {   // masks for round s outputs: planes d0+2s-2, d0+2s-1
        const size_t p0 = moff + (size_t)(d0 + 2 * s - 2) * HW;
        Mn  = make_float2(mask[p0], mask[p0 + W]);            // .x = row A, .y = row B
        Mn1 = make_float2(mask[p0 + HW], mask[p0 + HW + W]);
    };

    // rolling state: [array][row-in-pair][age]; ct post-shift: [1]=c(p), [0]=c(p-1)
    float dx[2][2][3], dy[2][2][3], sm[2][2][3], ct[2][2][2];
    #pragma unroll
    for (int a = 0; a < 2; ++a)
        #pragma unroll
        for (int o = 0; o < 2; ++o) {
            dx[a][o][0]=dx[a][o][1]=dx[a][o][2]=0.f;
            dy[a][o][0]=dy[a][o][1]=dy[a][o][2]=0.f;
            sm[a][o][0]=sm[a][o][1]=sm[a][o][2]=0.f;
            ct[a][o][0]=ct[a][o][1]=0.f;
        }
    float acc = 0.f;

    dma_pair(0);        // prefetch pair 0

    for (int s = 0; s < NPAIR; ++s) {
        // Wait for pair s's DMAs (youngest outstanding VMEM at this point; masks
        // issued earlier complete in-order before them). Depth-1 prefetch
        // (~7000cy/pair-slot) >> HBM latency, so a full drain here is fine
        // (proven: rounds 0/4/6 identical dur across sync structures).
        asm volatile("s_waitcnt vmcnt(0)" ::: "memory");
        __builtin_amdgcn_sched_barrier(0);
        __builtin_amdgcn_s_barrier();       // raw barrier: no compiler-forced drain
        __builtin_amdgcn_sched_barrier(0);

        Mc = Mn; Mc1 = Mn1;
        if (s + 1 < NPAIR) {
            load_mask(s + 1);               // masks first (in-order vmcnt: don't chain DMAs)
            dma_pair(s + 1);                // writes buf[(s+1)&1], readers done pre-barrier
        }

        const float* buf = lds + (s & 1) * BUFFLOATS;

        #pragma unroll
        for (int q = 0; q < 2; ++q) {
            const int p = d0 - 1 + 2 * s + q;

            #pragma unroll
            for (int a = 0; a < 2; ++a) {
                const int ab = (a * 2 + q) * LPLANE + (2 * wv) * LROW + col + 3;
                float e[4][3];
                #pragma unroll
                for (int rr = 0; rr < 4; ++rr)
                    #pragma unroll
                    for (int d = 0; d < 3; ++d)
                        e[rr][d] = buf[ab + rr * LROW + d];   // conflict-free (round 4)

                float rs[4], rd[4];
                #pragma unroll
                for (int rr = 0; rr < 4; ++rr) {
                    rs[rr] = e[rr][0] + 2.f * e[rr][1] + e[rr][2];
                    rd[rr] = e[rr][2] - e[rr][0];
                }
                #pragma unroll
                for (int o = 0; o < 2; ++o) {   // o = row within pair
                    dx[a][o][0] = dx[a][o][1]; dx[a][o][1] = dx[a][o][2];
                    dx[a][o][2] = rd[o] + 2.f * rd[o+1] + rd[o+2];
                    sm[a][o][0] = sm[a][o][1]; sm[a][o][1] = sm[a][o][2];
                    sm[a][o][2] = rs[o] + 2.f * rs[o+1] + rs[o+2];
                    dy[a][o][0] = dy[a][o][1]; dy[a][o][1] = dy[a][o][2];
                    dy[a][o][2] = rs[o] - rs[o+2];
                    ct[a][o][0] = ct[a][o][1]; ct[a][o][1] = e[o+1][1];
                }
            }

            if (p >= d0 + 1) {              // output plane od = p-1; ct[..][0] = c(p-1)
                const float2 M = q ? Mc1 : Mc;
                #pragma unroll
                for (int o = 0; o < 2; ++o) {
                    float gxa = dx[0][o][0] + 2.f * dx[0][o][1] + dx[0][o][2];
                    float gya = dy[0][o][0] + 2.f * dy[0][o][1] + dy[0][o][2];
                    float gza = sm[0][o][0] - sm[0][o][2];
                    float gxb = dx[1][o][0] + 2.f * dx[1][o][1] + dx[1][o][2];
                    float gyb = dy[1][o][0] + 2.f * dy[1][o][1] + dy[1][o][2];
                    float gzb = sm[1][o][0] - sm[1][o][2];
                    float ga = __builtin_amdgcn_sqrtf(gxa * gxa + gya * gya + gza * gza + 1e-10f);
                    float gb = __builtin_amdgcn_sqrtf(gxb * gxb + gyb * gyb + gzb * gzb + 1e-10f);
                    float m  = o ? M.y : M.x;
                    float dm = ct[0][o][0] - ct[1][o][0];
                    float mse = dm * dm * m;
                    float dg  = gb - ga;
                    float mge = dg * dg * m;
                    // tanh(x) = 1 - 2/(e^{2x}+1), x >= 0; saturates via inf -> rcp -> 0
                    float ex = __expf(2.f * mge);
                    float t  = 1.f - 2.f * __builtin_amdgcn_rcpf(ex + 1.f);
                    acc += mse * (1.f + t);
                }
            }
        }
    }

    // block reduction (8 waves)
    float v = acc;
    #pragma unroll
    for (int o = 32; o > 0; o >>= 1) v += __shfl_down(v, o, 64);
    if ((tid & 63) == 0) red[tid >> 6] = v;
    __syncthreads();
    if (tid == 0) {
        float bs = 0.f;
        #pragma unroll
        for (int i = 0; i < 8; ++i) bs += red[i];
        partials[(size_t)blockIdx.z * (GX * GY)
                 + (size_t)blockIdx.y * GX + blockIdx.x] = bs;
    }
}

__global__ __launch_bounds__(256) void reduce_final(
    const float* __restrict__ partials, int n, float* __restrict__ out)
{
    int tid = threadIdx.x;
    double s = 0.0;
    for (int i = tid; i < n; i += 256) s += (double)partials[i];
    #pragma unroll
    for (int o = 32; o > 0; o >>= 1) s += __shfl_down(s, o, 64);
    __shared__ double red[4];
    if ((tid & 63) == 0) red[tid >> 6] = s;
    __syncthreads();
    if (tid == 0) {
        double t = red[0] + red[1] + red[2] + red[3];
        const double ntot = (double)BATCH * (double)DEPTH * (double)H * (double)W;
        out[0] = (float)(t / ntot);
    }
}

extern "C" void kernel_launch(void* const* d_in, const int* in_sizes, int n_in,
                              void* d_out, int out_size, void* d_ws, size_t ws_size,
                              hipStream_t stream) {
    const float* pred = (const float*)d_in[0];
    const float* gt   = (const float*)d_in[1];
    const float* mask = (const float*)d_in[2];
    float* partials = (float*)d_ws;

    dim3 grid(GX, GY, BATCH);   // 36 x 16 x 2 = 1152
    sobel_loss_part<<<grid, NT, 0, stream>>>(pred, gt, mask, partials);

    reduce_final<<<1, 256, 0, stream>>>(partials, NBLK, (float*)d_out);
}

// Round 8
// 189.360 us; speedup vs baseline: 1.0219x; 1.0219x over previous
//
#include <hip/hip_runtime.h>
#include <math.h>

// [B=2, 1, D=192, H=192, W=192] fp32
#define W 192
#define H 192
#define DEPTH 192
#define BATCH 2
#define TW 64          // tile width
#define TH 8           // tile height (4 waves x row-pair)
#define DC 12          // output planes per block
#define HW (H * W)
#define VOL ((size_t)DEPTH * HW)
#define NPL (DC + 2)   // planes swept per block: d0-1 .. d0+12
#define GX ((W / TW) * (H / TH))      // 72
#define GY (DEPTH / DC)               // 16
#define NBLK (GX * GY * BATCH)        // 2304

// Rounds 0/4/6/7: dur 72-79us invariant across staging/sync/block-shape; occupancy
// pinned ~34% regardless of resources; VALU-issue conserved ~32us. Hypothesis: the
// per-pair full-block barrier convoy correlates all waves' stalls. This version has
// ZERO barriers and ZERO LDS in the hot path: each wave loads its own 4 stencil rows
// per plane directly from global (3 overlapping coalesced loads/row; L1/L2 serve the
// 2x row overlap between adjacent waves). Halo zero-padding via clamped addresses +
// 0/1 float masks folded into rs/rd. 14-plane loop fully unrolled: rolling state
// becomes SSA renames; compiler overlaps next-plane loads with current compute.
__global__ __launch_bounds__(256) void sobel_loss_part(
    const float* __restrict__ pred, const float* __restrict__ gt,
    const float* __restrict__ mask, float* __restrict__ partials)
{
    const int tid = threadIdx.x;
    const int tx = blockIdx.x % 3;          // W tile (0..2)
    const int ty = blockIdx.x / 3;          // H tile (0..23)
    const int w0 = tx * TW, h0 = ty * TH;
    const int d0 = blockIdx.y * DC;
    const size_t base = (size_t)blockIdx.z * VOL;

    const int wv  = tid >> 6;               // wave 0..3 -> row pair (2wv, 2wv+1)
    const int col = tid & 63;               // column 0..63
    const int colg = w0 + col;
    const int ra = h0 + 2 * wv;             // output row A (global); row B = ra+1

    // ---- plane-invariant geometry: stencil rows ra-1..ra+2, clamped + masked ----
    int yoff[4]; float rmask[4];
    #pragma unroll
    for (int r = 0; r < 4; ++r) {
        int y = ra - 1 + r;
        rmask[r] = ((unsigned)y < (unsigned)H) ? 1.f : 0.f;
        int yc = y < 0 ? 0 : (y > H - 1 ? H - 1 : y);
        yoff[r] = yc * W;
    }
    const float lmk = (colg > 0)     ? 1.f : 0.f;
    const float rmk = (colg < W - 1) ? 1.f : 0.f;
    const int cl = colg > 0     ? colg - 1 : 0;
    const int cr = colg < W - 1 ? colg + 1 : W - 1;

    const float* __restrict__ A0 = pred + base;
    const float* __restrict__ A1 = gt + base;
    const float* __restrict__ MB = mask + base + (size_t)ra * W + colg;  // + od*HW

    // rolling state: [array][row-in-pair][age]; ct post-shift: [1]=c(p), [0]=c(p-1)
    float dx[2][2][3], dy[2][2][3], sm[2][2][3], ct[2][2][2];
    #pragma unroll
    for (int a = 0; a < 2; ++a)
        #pragma unroll
        for (int o = 0; o < 2; ++o) {
            dx[a][o][0]=dx[a][o][1]=dx[a][o][2]=0.f;
            dy[a][o][0]=dy[a][o][1]=dy[a][o][2]=0.f;
            sm[a][o][0]=sm[a][o][1]=sm[a][o][2]=0.f;
            ct[a][o][0]=ct[a][o][1]=0.f;
        }
    float acc = 0.f;
    float2 Mc = make_float2(0.f, 0.f), Mn = make_float2(0.f, 0.f);

    #pragma unroll
    for (int i = 0; i < NPL; ++i) {
        const int p = d0 - 1 + i;
        const float pm = ((unsigned)p < (unsigned)DEPTH) ? 1.f : 0.f;  // only i=0 / i=13 can be OOB
        const int  pc = p < 0 ? 0 : (p > DEPTH - 1 ? DEPTH - 1 : p);
        const size_t pb = (size_t)pc * HW;

        // prefetch output-mask for next iteration's epilogue (od = p), one plane ahead
        if (i >= 1 && i <= DC) {
            const float* mp = MB + (size_t)p * HW;
            Mn = make_float2(mp[0], mp[W]);   // rows ra, ra+1 at plane p
        }

        float msk[4];
        #pragma unroll
        for (int r = 0; r < 4; ++r) msk[r] = rmask[r] * pm;

        float rs[2][4], rd[2][4], cc[2][2];
        #pragma unroll
        for (int a = 0; a < 2; ++a) {
            const float* src = (a ? A1 : A0) + pb;
            #pragma unroll
            for (int r = 0; r < 4; ++r) {
                const float* rp = src + yoff[r];
                float m = rp[colg];
                float l = rp[cl] * lmk;       // clamped addr, zeroed at true edge
                float q = rp[cr] * rmk;
                rs[a][r] = msk[r] * (l + 2.f * m + q);
                rd[a][r] = msk[r] * (q - l);
                if (r == 1) cc[a][0] = msk[r] * m;
                if (r == 2) cc[a][1] = msk[r] * m;
            }
        }

        #pragma unroll
        for (int a = 0; a < 2; ++a)
            #pragma unroll
            for (int o = 0; o < 2; ++o) {     // o = row within pair
                dx[a][o][0] = dx[a][o][1]; dx[a][o][1] = dx[a][o][2];
                dx[a][o][2] = rd[a][o] + 2.f * rd[a][o+1] + rd[a][o+2];
                sm[a][o][0] = sm[a][o][1]; sm[a][o][1] = sm[a][o][2];
                sm[a][o][2] = rs[a][o] + 2.f * rs[a][o+1] + rs[a][o+2];
                dy[a][o][0] = dy[a][o][1]; dy[a][o][1] = dy[a][o][2];
                dy[a][o][2] = rs[a][o] - rs[a][o+2];
                ct[a][o][0] = ct[a][o][1]; ct[a][o][1] = cc[a][o];
            }

        if (i >= 2) {                         // output plane od = p-1; ct[..][0] = c(od)
            const float2 M = Mc;
            #pragma unroll
            for (int o = 0; o < 2; ++o) {
                float gxa = dx[0][o][0] + 2.f * dx[0][o][1] + dx[0][o][2];
                float gya = dy[0][o][0] + 2.f * dy[0][o][1] + dy[0][o][2];
                float gza = sm[0][o][0] - sm[0][o][2];
                float gxb = dx[1][o][0] + 2.f * dx[1][o][1] + dx[1][o][2];
                float gyb = dy[1][o][0] + 2.f * dy[1][o][1] + dy[1][o][2];
                float gzb = sm[1][o][0] - sm[1][o][2];
                float ga = __builtin_amdgcn_sqrtf(gxa * gxa + gya * gya + gza * gza + 1e-10f);
                float gb = __builtin_amdgcn_sqrtf(gxb * gxb + gyb * gyb + gzb * gzb + 1e-10f);
                float m  = o ? M.y : M.x;
                float dm = ct[0][o][0] - ct[1][o][0];
                float mse = dm * dm * m;
                float dg  = gb - ga;
                float mge = dg * dg * m;
                // tanh(x) = 1 - 2/(e^{2x}+1), x >= 0; saturates via inf -> rcp -> 0
                float ex = __expf(2.f * mge);
                float t  = 1.f - 2.f * __builtin_amdgcn_rcpf(ex + 1.f);
                acc += mse * (1.f + t);
            }
        }
        Mc = Mn;
    }

    // block reduction (only sync in the kernel)
    float v = acc;
    #pragma unroll
    for (int o = 32; o > 0; o >>= 1) v += __shfl_down(v, o, 64);
    __shared__ float red[4];
    if ((tid & 63) == 0) red[tid >> 6] = v;
    __syncthreads();
    if (tid == 0) {
        partials[(size_t)blockIdx.z * (GX * GY)
                 + (size_t)blockIdx.y * GX + blockIdx.x]
            = red[0] + red[1] + red[2] + red[3];
    }
}

__global__ __launch_bounds__(256) void reduce_final(
    const float* __restrict__ partials, int n, float* __restrict__ out)
{
    int tid = threadIdx.x;
    double s = 0.0;
    for (int i = tid; i < n; i += 256) s += (double)partials[i];
    #pragma unroll
    for (int o = 32; o > 0; o >>= 1) s += __shfl_down(s, o, 64);
    __shared__ double red[4];
    if ((tid & 63) == 0) red[tid >> 6] = s;
    __syncthreads();
    if (tid == 0) {
        double t = red[0] + red[1] + red[2] + red[3];
        const double ntot = (double)BATCH * (double)DEPTH * (double)H * (double)W;
        out[0] = (float)(t / ntot);
    }
}

extern "C" void kernel_launch(void* const* d_in, const int* in_sizes, int n_in,
                              void* d_out, int out_size, void* d_ws, size_t ws_size,
                              hipStream_t stream) {
    const float* pred = (const float*)d_in[0];
    const float* gt   = (const float*)d_in[1];
    const float* mask = (const float*)d_in[2];
    float* partials = (float*)d_ws;

    dim3 grid(GX, GY, BATCH);   // 72 x 16 x 2 = 2304
    sobel_loss_part<<<grid, 256, 0, stream>>>(pred, gt, mask, partials);

    reduce_final<<<1, 256, 0, stream>>>(partials, NBLK, (float*)d_out);
}